// Round 1
// baseline (622.571 us; speedup 1.0000x reference)
//
#include <hip/hip_runtime.h>

#define RAD 6
#define KS 13
#define DIM 192
#define CH 3

// Extract the 1D gaussian from the 3D kernel: since g3[i][j][k] = g1[i]*g1[j]*g1[k]
// and sum(g1)=1, the row-sum over (j,k) recovers g1[i] exactly (up to fp rounding).
__global__ void g1_extract_kernel(const float* __restrict__ w, float* __restrict__ g1) {
    int i = threadIdx.x;
    if (i < KS) {
        float s = 0.f;
        for (int j = 0; j < KS * KS; ++j) s += w[i * KS * KS + j];
        g1[i] = s;
    }
}

// 1D conv along an axis with compile-time stride. Zero padding at the ends.
// Consecutive threads -> consecutive flat index -> consecutive innermost (W)
// coordinate -> every tap load is a coalesced wave load.
template <int STRIDE>
__global__ void conv1d_kernel(const float* __restrict__ in, float* __restrict__ out,
                              const float* __restrict__ g1, int total) {
    int n = blockIdx.x * blockDim.x + threadIdx.x;
    if (n >= total) return;

    float wreg[KS];
#pragma unroll
    for (int t = 0; t < KS; ++t) wreg[t] = g1[t];

    int pos = (n / STRIDE) % DIM;  // position along the conv axis (compile-time magic div)
    float acc = 0.f;
#pragma unroll
    for (int t = 0; t < KS; ++t) {
        int p = pos + t - RAD;
        if (p >= 0 && p < DIM) acc += wreg[t] * in[n + (t - RAD) * STRIDE];
    }
    out[n] = acc;
}

// Fallback: direct 2197-tap depthwise conv (only if ws_size is too small).
__global__ void naive_conv3d_kernel(const float* __restrict__ x, const float* __restrict__ w,
                                    float* __restrict__ out, int total) {
    int n = blockIdx.x * blockDim.x + threadIdx.x;
    if (n >= total) return;
    int wp = n % DIM;
    int h  = (n / DIM) % DIM;
    int d  = (n / (DIM * DIM)) % DIM;
    int c  = n / (DIM * DIM * DIM);
    const float* wc = w + c * KS * KS * KS;
    const float* xc = x + (size_t)c * DIM * DIM * DIM;
    float acc = 0.f;
    for (int kd = 0; kd < KS; ++kd) {
        int dd = d + kd - RAD;
        if (dd < 0 || dd >= DIM) continue;
        for (int kh = 0; kh < KS; ++kh) {
            int hh = h + kh - RAD;
            if (hh < 0 || hh >= DIM) continue;
            for (int kw = 0; kw < KS; ++kw) {
                int ww = wp + kw - RAD;
                if (ww < 0 || ww >= DIM) continue;
                acc += wc[(kd * KS + kh) * KS + kw] * xc[((size_t)dd * DIM + hh) * DIM + ww];
            }
        }
    }
    out[n] = acc;
}

extern "C" void kernel_launch(void* const* d_in, const int* in_sizes, int n_in,
                              void* d_out, int out_size, void* d_ws, size_t ws_size,
                              hipStream_t stream) {
    const float* x = (const float*)d_in[0];
    const float* w = (const float*)d_in[1];
    float* out = (float*)d_out;

    const int total = CH * DIM * DIM * DIM;  // 21,233,664
    const size_t inter_bytes = (size_t)total * sizeof(float);  // ~85 MB

    const int threads = 256;
    const int blocks = (total + threads - 1) / threads;

    if (ws_size >= inter_bytes + 64) {
        float* inter = (float*)d_ws;
        float* g1 = (float*)((char*)d_ws + inter_bytes);

        g1_extract_kernel<<<1, 64, 0, stream>>>(w, g1);
        // Pass 1: along W (stride 1):      x -> out
        conv1d_kernel<1><<<blocks, threads, 0, stream>>>(x, out, g1, total);
        // Pass 2: along H (stride 192):    out -> inter
        conv1d_kernel<DIM><<<blocks, threads, 0, stream>>>(out, inter, g1, total);
        // Pass 3: along D (stride 192^2):  inter -> out
        conv1d_kernel<DIM * DIM><<<blocks, threads, 0, stream>>>(inter, out, g1, total);
    } else {
        naive_conv3d_kernel<<<blocks, threads, 0, stream>>>(x, w, out, total);
    }
}

// Round 2
// 236.751 us; speedup vs baseline: 2.6296x; 2.6296x over previous
//
#include <hip/hip_runtime.h>

#define RAD 6
#define KS 13
#define DIM 192
#define CH 3
#define W4C (DIM / 4)          // 48 float4s per row
#define VOL (DIM * DIM * DIM)  // 7,077,888
#define TOTAL (CH * VOL)       // 21,233,664

// Extract 1D gaussian from the 3D kernel: g3[i][j][k] = g1[i]*g1[j]*g1[k], sum(g1)=1,
// so the row-sum over (j,k) recovers g1[i].
__global__ void g1_extract_kernel(const float* __restrict__ w, float* __restrict__ g1) {
    int i = threadIdx.x;
    if (i < KS) {
        float s = 0.f;
        for (int j = 0; j < KS * KS; ++j) s += w[i * KS * KS + j];
        g1[i] = s;
    }
}

// W-axis pass (contiguous axis). Each thread produces one float4 of outputs,
// reading 5 aligned float4s (fast path) covering taps [w-8, w+12).
__global__ __launch_bounds__(256) void conv_w_kernel(const float* __restrict__ in,
                                                     float* __restrict__ out,
                                                     const float* __restrict__ g1) {
    int q = blockIdx.x * 256 + threadIdx.x;  // float4 flat index (grid exact)
    float g[KS];
#pragma unroll
    for (int k = 0; k < KS; ++k) g[k] = g1[k];

    int w4 = q % W4C;
    const float4* in4 = (const float4*)in;
    float f[20];
    if (w4 >= 2 && w4 <= W4C - 3) {
#pragma unroll
        for (int b = 0; b < 5; ++b) {
            float4 v = in4[q + b - 2];
            f[4 * b + 0] = v.x; f[4 * b + 1] = v.y;
            f[4 * b + 2] = v.z; f[4 * b + 3] = v.w;
        }
    } else {
        int row = (q / W4C) * DIM;  // float index of row start
        int w = w4 * 4;
#pragma unroll
        for (int j = 0; j < 20; ++j) {
            int ww = w - 8 + j;
            f[j] = (ww >= 0 && ww < DIM) ? in[row + ww] : 0.f;
        }
    }
    float4 o; o.x = o.y = o.z = o.w = 0.f;
#pragma unroll
    for (int k = 0; k < KS; ++k) {
        o.x += g[k] * f[k + 2];
        o.y += g[k] * f[k + 3];
        o.z += g[k] * f[k + 4];
        o.w += g[k] * f[k + 5];
    }
    ((float4*)out)[q] = o;
}

// Strided-axis pass: each thread owns a float4-wide column SEGMENT along the axis,
// streaming sequentially with a 13-deep circular register window.
// AX4 = axis stride in float4 units; OT4 = stride of the other (non-w) coord.
// One float4 load + one float4 store per 4 outputs; purely sequential along axis.
template <int AX4, int OT4>
__global__ __launch_bounds__(256) void conv_col_kernel(const float* __restrict__ in,
                                                       float* __restrict__ out,
                                                       const float* __restrict__ g1) {
    const int COLS = CH * DIM * W4C;  // 27648 column-groups
    const int L = 48;                 // outputs per thread along the axis (192/4 segs)
    int t = blockIdx.x * 256 + threadIdx.x;  // < 4*COLS = 110592 (grid exact)
    int seg = t / COLS;               // blocks don't straddle segs (108 blocks/seg)
    int colid = t % COLS;
    int c = colid / (DIM * W4C);
    int rem = colid % (DIM * W4C);
    int other = rem / W4C;
    int w4 = rem % W4C;
    size_t base4 = (size_t)c * (VOL / 4) + (size_t)other * OT4 + (size_t)w4;

    const float4* in4 = (const float4*)in;
    float4* out4 = (float4*)out;

    float g[KS];
#pragma unroll
    for (int k = 0; k < KS; ++k) g[k] = g1[k];

    const float4 z4 = make_float4(0.f, 0.f, 0.f, 0.f);
    int d0 = seg * L;

    // Circular window: before step i (global d = d0+i), buf[(i+j)%13] = x[d-6+j].
    float4 buf[KS];
#pragma unroll
    for (int j = 0; j < KS; ++j) {
        int dd = d0 - RAD + j;
        buf[j] = (dd >= 0 && dd < DIM) ? in4[base4 + (size_t)dd * AX4] : z4;
    }

    int d = d0;
    auto body = [&](int s) {  // s = i % 13, compile-time after unroll
        int dl = d + RAD + 1;
        float4 nv = (dl < DIM) ? in4[base4 + (size_t)dl * AX4] : z4;  // prefetch first
        float4 a; a.x = a.y = a.z = a.w = 0.f;
#pragma unroll
        for (int j = 0; j < KS; ++j) {
            const float4 v = buf[(s + j) % KS];
            float gw = g[j];
            a.x += gw * v.x; a.y += gw * v.y; a.z += gw * v.z; a.w += gw * v.w;
        }
        out4[base4 + (size_t)d * AX4] = a;
        buf[s] = nv;  // commit after compute (slot s held x[d-6], now dead)
        ++d;
    };

    for (int chunk = 0; chunk < 3; ++chunk) {  // 48 = 3*13 + 9
#pragma unroll
        for (int s = 0; s < KS; ++s) body(s);
    }
#pragma unroll
    for (int s = 0; s < 9; ++s) body(s);
}

// Fallback: direct 2197-tap depthwise conv (only if ws_size is too small).
__global__ void naive_conv3d_kernel(const float* __restrict__ x, const float* __restrict__ w,
                                    float* __restrict__ out, int total) {
    int n = blockIdx.x * blockDim.x + threadIdx.x;
    if (n >= total) return;
    int wp = n % DIM;
    int h = (n / DIM) % DIM;
    int d = (n / (DIM * DIM)) % DIM;
    int c = n / (DIM * DIM * DIM);
    const float* wc = w + c * KS * KS * KS;
    const float* xc = x + (size_t)c * DIM * DIM * DIM;
    float acc = 0.f;
    for (int kd = 0; kd < KS; ++kd) {
        int dd = d + kd - RAD;
        if (dd < 0 || dd >= DIM) continue;
        for (int kh = 0; kh < KS; ++kh) {
            int hh = h + kh - RAD;
            if (hh < 0 || hh >= DIM) continue;
            for (int kw = 0; kw < KS; ++kw) {
                int ww = wp + kw - RAD;
                if (ww < 0 || ww >= DIM) continue;
                acc += wc[(kd * KS + kh) * KS + kw] * xc[((size_t)dd * DIM + hh) * DIM + ww];
            }
        }
    }
    out[n] = acc;
}

extern "C" void kernel_launch(void* const* d_in, const int* in_sizes, int n_in,
                              void* d_out, int out_size, void* d_ws, size_t ws_size,
                              hipStream_t stream) {
    const float* x = (const float*)d_in[0];
    const float* w = (const float*)d_in[1];
    float* out = (float*)d_out;

    const size_t inter_bytes = (size_t)TOTAL * sizeof(float);  // ~85 MB

    if (ws_size >= inter_bytes + 64) {
        float* inter = (float*)d_ws;
        float* g1 = (float*)((char*)d_ws + inter_bytes);

        g1_extract_kernel<<<1, 64, 0, stream>>>(w, g1);

        // Pass 1: W axis (contiguous), x -> out.  20736 blocks exact.
        conv_w_kernel<<<TOTAL / 4 / 256, 256, 0, stream>>>(x, out, g1);

        // Pass 2: H axis (stride DIM; other coord = d, stride DIM^2), out -> inter.
        conv_col_kernel<DIM / 4, DIM * DIM / 4>
            <<<(4 * CH * DIM * W4C) / 256, 256, 0, stream>>>(out, inter, g1);

        // Pass 3: D axis (stride DIM^2; other coord = h, stride DIM), inter -> out.
        conv_col_kernel<DIM * DIM / 4, DIM / 4>
            <<<(4 * CH * DIM * W4C) / 256, 256, 0, stream>>>(inter, out, g1);
    } else {
        const int threads = 256;
        const int blocks = (TOTAL + threads - 1) / threads;
        naive_conv3d_kernel<<<blocks, threads, 0, stream>>>(x, w, out, TOTAL);
    }
}

// Round 3
// 211.072 us; speedup vs baseline: 2.9496x; 1.1217x over previous
//
#include <hip/hip_runtime.h>

#define RAD 6
#define KS 13
#define DIM 192
#define CH 3
#define W4C (DIM / 4)          // 48 float4s per row
#define VOL (DIM * DIM * DIM)  // 7,077,888
#define TOTAL (CH * VOL)       // 21,233,664

// Extract 1D gaussian from the 3D kernel: g3[i][j][k] = g1[i]*g1[j]*g1[k], sum(g1)=1,
// so the row-sum over (j,k) recovers g1[i].
__global__ void g1_extract_kernel(const float* __restrict__ w, float* __restrict__ g1) {
    int i = threadIdx.x;
    if (i < KS) {
        float s = 0.f;
        for (int j = 0; j < KS * KS; ++j) s += w[i * KS * KS + j];
        g1[i] = s;
    }
}

// W-axis pass (contiguous axis). Each thread produces one float4 of outputs from
// 5 aligned float4 loads covering taps [w-8, w+12). WAVE-UNIFORM: boundary
// handling is clamp-index + per-element zeroing (no divergent scalar path --
// with W4C=48 < wave=64, every wave would otherwise diverge).
__global__ __launch_bounds__(256) void conv_w_kernel(const float* __restrict__ in,
                                                     float* __restrict__ out,
                                                     const float* __restrict__ g1) {
    int q = blockIdx.x * 256 + threadIdx.x;  // float4 flat index (grid exact)
    float g[KS];
#pragma unroll
    for (int k = 0; k < KS; ++k) g[k] = g1[k];

    int w4 = q % W4C;
    int w0 = w4 * 4;
    const float4* in4 = (const float4*)in;

    float f[20];
#pragma unroll
    for (int b = 0; b < 5; ++b) {
        int idx = q + b - 2;
        idx = min(max(idx, 0), TOTAL / 4 - 1);  // stay in the array; values fixed below
        float4 v = in4[idx];
        f[4 * b + 0] = v.x; f[4 * b + 1] = v.y;
        f[4 * b + 2] = v.z; f[4 * b + 3] = v.w;
    }
    // Zero taps that fall outside this row (handles both row crossing and clamp).
#pragma unroll
    for (int j = 0; j < 20; ++j) {
        int ww = w0 - 8 + j;
        if (ww < 0 || ww >= DIM) f[j] = 0.f;
    }

    float4 o; o.x = o.y = o.z = o.w = 0.f;
#pragma unroll
    for (int k = 0; k < KS; ++k) {
        o.x += g[k] * f[k + 2];
        o.y += g[k] * f[k + 3];
        o.z += g[k] * f[k + 4];
        o.w += g[k] * f[k + 5];
    }
    ((float4*)out)[q] = o;
}

// Strided-axis pass: each thread owns a float4-wide column SEGMENT along the axis,
// streaming sequentially with a 13-deep circular register window.
// AX4 = axis stride in float4 units; OT4 = stride of the other (non-w) coord.
// SEGS=8 (L=24): 221184 threads = 3456 waves = 13.5 waves/CU for latency hiding.
template <int AX4, int OT4>
__global__ __launch_bounds__(256) void conv_col_kernel(const float* __restrict__ in,
                                                       float* __restrict__ out,
                                                       const float* __restrict__ g1) {
    const int COLS = CH * DIM * W4C;  // 27648 column-groups
    const int SEGS = 8;
    const int L = DIM / SEGS;         // 24 outputs per thread along the axis
    int t = blockIdx.x * 256 + threadIdx.x;  // < SEGS*COLS (grid exact)
    int seg = t / COLS;               // blocks don't straddle segs (108 blocks/seg)
    int colid = t % COLS;
    int c = colid / (DIM * W4C);
    int rem = colid % (DIM * W4C);
    int other = rem / W4C;
    int w4 = rem % W4C;
    size_t base4 = (size_t)c * (VOL / 4) + (size_t)other * OT4 + (size_t)w4;

    const float4* in4 = (const float4*)in;
    float4* out4 = (float4*)out;

    float g[KS];
#pragma unroll
    for (int k = 0; k < KS; ++k) g[k] = g1[k];

    const float4 z4 = make_float4(0.f, 0.f, 0.f, 0.f);
    int d0 = seg * L;

    // Circular window: before step i (global d = d0+i), buf[(i+j)%13] = x[d-6+j].
    float4 buf[KS];
#pragma unroll
    for (int j = 0; j < KS; ++j) {
        int dd = d0 - RAD + j;
        buf[j] = (dd >= 0 && dd < DIM) ? in4[base4 + (size_t)dd * AX4] : z4;
    }

    int d = d0;
    auto body = [&](int s) {  // s = i % 13, compile-time after unroll
        int dl = d + RAD + 1;
        float4 nv = (dl < DIM) ? in4[base4 + (size_t)dl * AX4] : z4;  // prefetch first
        float4 a; a.x = a.y = a.z = a.w = 0.f;
#pragma unroll
        for (int j = 0; j < KS; ++j) {
            const float4 v = buf[(s + j) % KS];
            float gw = g[j];
            a.x += gw * v.x; a.y += gw * v.y; a.z += gw * v.z; a.w += gw * v.w;
        }
        out4[base4 + (size_t)d * AX4] = a;
        buf[s] = nv;  // commit after compute (slot s held x[d-6], now dead)
        ++d;
    };

    // L = 24 = 13 + 11
#pragma unroll
    for (int s = 0; s < KS; ++s) body(s);
#pragma unroll
    for (int s = 0; s < 11; ++s) body(s);
}

// Fallback: direct 2197-tap depthwise conv (only if ws_size is too small).
__global__ void naive_conv3d_kernel(const float* __restrict__ x, const float* __restrict__ w,
                                    float* __restrict__ out, int total) {
    int n = blockIdx.x * blockDim.x + threadIdx.x;
    if (n >= total) return;
    int wp = n % DIM;
    int h = (n / DIM) % DIM;
    int d = (n / (DIM * DIM)) % DIM;
    int c = n / (DIM * DIM * DIM);
    const float* wc = w + c * KS * KS * KS;
    const float* xc = x + (size_t)c * DIM * DIM * DIM;
    float acc = 0.f;
    for (int kd = 0; kd < KS; ++kd) {
        int dd = d + kd - RAD;
        if (dd < 0 || dd >= DIM) continue;
        for (int kh = 0; kh < KS; ++kh) {
            int hh = h + kh - RAD;
            if (hh < 0 || hh >= DIM) continue;
            for (int kw = 0; kw < KS; ++kw) {
                int ww = wp + kw - RAD;
                if (ww < 0 || ww >= DIM) continue;
                acc += wc[(kd * KS + kh) * KS + kw] * xc[((size_t)dd * DIM + hh) * DIM + ww];
            }
        }
    }
    out[n] = acc;
}

extern "C" void kernel_launch(void* const* d_in, const int* in_sizes, int n_in,
                              void* d_out, int out_size, void* d_ws, size_t ws_size,
                              hipStream_t stream) {
    const float* x = (const float*)d_in[0];
    const float* w = (const float*)d_in[1];
    float* out = (float*)d_out;

    const size_t inter_bytes = (size_t)TOTAL * sizeof(float);  // ~85 MB

    if (ws_size >= inter_bytes + 64) {
        float* inter = (float*)d_ws;
        float* g1 = (float*)((char*)d_ws + inter_bytes);

        g1_extract_kernel<<<1, 64, 0, stream>>>(w, g1);

        // Pass 1: W axis (contiguous), x -> out.  20736 blocks exact.
        conv_w_kernel<<<TOTAL / 4 / 256, 256, 0, stream>>>(x, out, g1);

        // Pass 2: H axis (stride DIM; other coord = d, stride DIM^2), out -> inter.
        conv_col_kernel<DIM / 4, DIM * DIM / 4>
            <<<(8 * CH * DIM * W4C) / 256, 256, 0, stream>>>(out, inter, g1);

        // Pass 3: D axis (stride DIM^2; other coord = h, stride DIM), inter -> out.
        conv_col_kernel<DIM * DIM / 4, DIM / 4>
            <<<(8 * CH * DIM * W4C) / 256, 256, 0, stream>>>(inter, out, g1);
    } else {
        const int threads = 256;
        const int blocks = (TOTAL + threads - 1) / threads;
        naive_conv3d_kernel<<<blocks, threads, 0, stream>>>(x, w, out, TOTAL);
    }
}